// Round 11
// baseline (505.137 us; speedup 1.0000x reference)
//
#include <hip/hip_runtime.h>

#define B 8
#define N 256
#define H 128
#define NF 6
#define EF 15
#define TD 4
#define FH 64
#define M (B*N)

// R11 NOTE: bodies are byte-identical to the R6 (73.8 us) version. Each kernel
// is launched REPS times (idempotent re-computation) purely so per-kernel
// dur_us rises above the 40 us harness fills and becomes visible in the
// rocprof top-5. Remove the loops after reading the breakdown.
#define REPS 8

typedef unsigned short u16;
using short8  = __attribute__((ext_vector_type(8))) short;
using short4v = __attribute__((ext_vector_type(4))) short;
using f32x4   = __attribute__((ext_vector_type(4))) float;

__device__ __forceinline__ u16 f2bf(float x) {
    unsigned u = __float_as_uint(x);
    u += 0x7fffu + ((u >> 16) & 1u);
    return (u16)(u >> 16);
}
__device__ __forceinline__ float bf2f(u16 h) {
    return __uint_as_float(((unsigned)h) << 16);
}

// ---------------------------------------------------------------------------
// Depth-2 staging pipeline (R6).
#define PIPE(NC, LD, COMP)                          \
    LD(0, pA0, pA1);                                \
    LD(1, pB0, pB1);                                \
    WRX(0, pA0, pA1);                               \
    __syncthreads();                                \
    _Pragma("unroll")                               \
    for (int c = 0; c < (NC); c += 2) {             \
        WRX(1, pB0, pB1);                           \
        if (c + 2 < (NC)) LD(c + 2, pA0, pA1);      \
        COMP(c, 0);                                 \
        __syncthreads();                            \
        if (c + 2 < (NC)) WRX(0, pA0, pA1);         \
        if (c + 3 < (NC)) LD(c + 3, pB0, pB1);      \
        COMP(c + 1, 1);                             \
        __syncthreads();                            \
    }

// ---------------------------------------------------------------------------
// k_setup: role split by blockIdx.x (grid 3072, 256 thr). (R6 body.)
__global__ __launch_bounds__(256) void k_setup(
    const float* __restrict__ edge, const int* __restrict__ adj,
    const float* __restrict__ nf, const float* __restrict__ Wemb,
    const float* __restrict__ bemb,
    const float* __restrict__ msg_W, const float* __restrict__ upd_W,
    const float* __restrict__ W1,
    float* __restrict__ e0p, float* __restrict__ e1p, float* __restrict__ e2p,
    float* __restrict__ rp0, float* __restrict__ rp1, float* __restrict__ rp2,
    float* __restrict__ deg,
    u16* __restrict__ WeTh, u16* __restrict__ WeTl,
    u16* __restrict__ UwTh, u16* __restrict__ UwTl,
    u16* __restrict__ W1Th, u16* __restrict__ W1Tl,
    u16* __restrict__ eRh, u16* __restrict__ eRl,
    u16* __restrict__ eTh, u16* __restrict__ eTl)
{
    __shared__ __align__(16) float smem[3848];
    __shared__ float red[4];
    const int t = threadIdx.x;
    const int blk = blockIdx.x;

    if (blk < 2048) {
        const int i = blk & 255;
        const float* src = edge + (size_t)blk * (N * EF);
        float4* s4 = (float4*)smem;
#pragma unroll
        for (int u = 0; u < 4; ++u) {
            int idx = t + u * 256;
            if (idx < (N * EF) / 4) s4[idx] = *(const float4*)(src + idx * 4);
        }
        __syncthreads();
        const int j = t;
        float e0 = smem[j * EF + 12];
        float e1 = smem[j * EF + 13];
        float e2 = smem[j * EF + 14];
        size_t base = (size_t)blk * N + j;
        e0p[base] = e0; e1p[base] = e1; e2p[base] = e2;
        float m = (adj[j * N + i] > 0) ? 1.f : 0.f;
        rp0[base] = m * e0; rp1[base] = m * e1; rp2[base] = m * e2;
    } else if (blk < 2688) {
        int idx = (blk - 2048) * 256 + t;
        float v; u16 *dh, *dl; int d;
        if (idx < 3 * 16384) {
            int l = idx / 16384, r = idx & 16383;
            int c = r >> 7, h = r & 127;
            v = msg_W[l * ((H + 3) * H) + h * H + c];
            dh = WeTh; dl = WeTl; d = idx;
        } else if (idx < 3 * 16384 + 3 * 32768) {
            int r0 = idx - 3 * 16384;
            int l = r0 / 32768, r = r0 & 32767;
            int c = r >> 8, k = r & 255;
            v = upd_W[l * (2 * H * H) + k * H + c];
            dh = UwTh; dl = UwTl; d = r0;
        } else {
            int r0 = idx - 3 * 16384 - 3 * 32768;
            int f = r0 >> 8, k = r0 & 255;
            v = W1[k * FH + f];
            dh = W1Th; dl = W1Tl; d = r0;
        }
        u16 h = f2bf(v);
        dh[d] = h;
        dl[d] = f2bf(v - bf2f(h));
    } else if (blk < 2816) {
        int tile = blk - 2688;
        float (*sout)[132] = (float(*)[132])smem;
        {
            int row = t >> 4, h0 = (t & 15) * 8;
            int gr = tile * 16 + row;
            float xv[NF];
#pragma unroll
            for (int k = 0; k < NF; ++k) xv[k] = nf[gr * NF + k];
#pragma unroll
            for (int c = 0; c < 8; ++c) {
                float a = bemb[h0 + c];
#pragma unroll
                for (int k = 0; k < NF; ++k) a += xv[k] * Wemb[k * H + h0 + c];
                sout[row][h0 + c] = fmaxf(a, 0.f);
            }
        }
        __syncthreads();
        {
            int row = t >> 4, h0 = (t & 15) * 8;
            int gr = tile * 16 + row;
            short8 ph, pl;
#pragma unroll
            for (int c = 0; c < 8; ++c) {
                float x = sout[row][h0 + c];
                u16 h = f2bf(x);
                ph[c] = (short)h;
                pl[c] = (short)f2bf(x - bf2f(h));
            }
            *(short8*)&eRh[(size_t)gr * H + h0] = ph;
            *(short8*)&eRl[(size_t)gr * H + h0] = pl;
        }
        {
            int hh = t >> 1, jj = (t & 1) * 8;
            short8 th, tl;
#pragma unroll
            for (int r = 0; r < 8; ++r) {
                float x = sout[jj + r][hh];
                u16 h = f2bf(x);
                th[r] = (short)h;
                tl[r] = (short)f2bf(x - bf2f(h));
            }
            size_t o = (size_t)(tile >> 4) * H * N + (size_t)hh * N + ((tile & 15) * 16) + jj;
            *(short8*)&eTh[o] = th;
            *(short8*)&eTl[o] = tl;
        }
    } else {
        int jr = blk - 2816;
        float v = (adj[jr * N + t] > 0) ? 1.f : 0.f;
        for (int o = 32; o > 0; o >>= 1) v += __shfl_down(v, o);
        if ((t & 63) == 0) red[t >> 6] = v;
        __syncthreads();
        if (t == 0) deg[jr] = red[0] + red[1] + red[2] + red[3];
    }
}

// ---------------------------------------------------------------------------
// k_layer: MFMA bf16 hi/lo-split fused GNN layer. (R6 body.)
template <bool FIRST, bool LAST>
__global__ __launch_bounds__(512) void k_layer(
    const u16* __restrict__ embR_hi, const u16* __restrict__ embR_lo,
    const u16* __restrict__ embT_hi, const u16* __restrict__ embT_lo,
    const int* __restrict__ adj,
    const float* __restrict__ rp0, const float* __restrict__ rp1,
    const float* __restrict__ rp2, float* __restrict__ ragg,
    const float* __restrict__ deg,
    const u16* __restrict__ WeT_hi, const u16* __restrict__ WeT_lo,
    const float* __restrict__ mwl, const float* __restrict__ mbl,
    const u16* __restrict__ UwT_hi, const u16* __restrict__ UwT_lo,
    const float* __restrict__ ubl,
    u16* __restrict__ oR_hi, u16* __restrict__ oR_lo,
    u16* __restrict__ oT_hi, u16* __restrict__ oT_lo,
    const u16* __restrict__ W1T_hi, const u16* __restrict__ W1T_lo,
    float* __restrict__ hi_out, float* __restrict__ hj_out)
{
    __shared__ __align__(16) u16 sbt[2][2][128][40];
    __shared__ __align__(16) u16 smask[16][264];
    __shared__ __align__(16) u16 semb_hi[16][136], semb_lo[16][136];
    __shared__ __align__(16) u16 sagg_hi[16][136], sagg_lo[16][136];
    __shared__ __align__(16) u16 smsg_hi[16][136], smsg_lo[16][136];
    __shared__ __align__(16) float sout[16][132];
    __shared__ float sragg[16][4];

    const int t = threadIdx.x;
    const int wave = t >> 6, lane = t & 63;
    const int lrow = lane & 15;
    const int kg8  = (lane >> 4) * 8;
    const int rb   = (lane >> 4) * 4;
    const int cb   = wave * 16;
    const int blk  = blockIdx.x;
    const int b    = blk >> 4, tile = blk & 15;
    const int j0   = tile * 16;
    const int gb   = b * N;

    const int sp = t >> 8, task = t & 255;
    const int sh = task >> 2, sseg = (task & 3) * 8;

    short8 pA0, pA1, pB0, pB1;

    {
        int j = t >> 5, i0 = (t & 31) * 8;
        int4 a0 = *(const int4*)(adj + (j0 + j) * N + i0);
        int4 a1 = *(const int4*)(adj + (j0 + j) * N + i0 + 4);
        short8 mrow;
        mrow[0] = (a0.x > 0) ? (short)0x3F80 : (short)0;
        mrow[1] = (a0.y > 0) ? (short)0x3F80 : (short)0;
        mrow[2] = (a0.z > 0) ? (short)0x3F80 : (short)0;
        mrow[3] = (a0.w > 0) ? (short)0x3F80 : (short)0;
        mrow[4] = (a1.x > 0) ? (short)0x3F80 : (short)0;
        mrow[5] = (a1.y > 0) ? (short)0x3F80 : (short)0;
        mrow[6] = (a1.z > 0) ? (short)0x3F80 : (short)0;
        mrow[7] = (a1.w > 0) ? (short)0x3F80 : (short)0;
        *(short8*)&smask[j][i0] = mrow;
        int h0 = (t & 31) * 4;
        *(short4v*)&semb_hi[j][h0] = *(const short4v*)&embR_hi[(size_t)(gb + j0 + j) * H + h0];
        *(short4v*)&semb_lo[j][h0] = *(const short4v*)&embR_lo[(size_t)(gb + j0 + j) * H + h0];
    }

    if constexpr (FIRST) {
        int j16 = t >> 5, ic = t & 31;
        int gj = gb + j0 + j16;
        float s0 = 0.f, s1 = 0.f, s2 = 0.f;
#pragma unroll
        for (int k = 0; k < 8; ++k) {
            size_t o = ((size_t)(gb + ic * 8 + k)) * N + (j0 + j16);
            s0 += rp0[o]; s1 += rp1[o]; s2 += rp2[o];
        }
        for (int o = 16; o > 0; o >>= 1) {
            s0 += __shfl_down(s0, o, 32);
            s1 += __shfl_down(s1, o, 32);
            s2 += __shfl_down(s2, o, 32);
        }
        if (ic == 0) {
            sragg[j16][0] = s0; sragg[j16][1] = s1; sragg[j16][2] = s2;
            float* rg = ragg + (size_t)gj * 3;
            rg[0] = s0; rg[1] = s1; rg[2] = s2;
        }
    } else {
        if (t < 48) sragg[t / 3][t % 3] = ragg[(size_t)(gb + j0 + t / 3) * 3 + (t % 3)];
    }

    const u16* sA_hi = embT_hi + (size_t)b * H * N;
    const u16* sA_lo = embT_lo + (size_t)b * H * N;

#define WRX(buf, q0, q1)                              \
    { *(short8*)&sbt[buf][sp][sh][sseg] = q0;         \
      *(short8*)&sbt[buf][sp][sh + 64][sseg] = q1; }

#define LDA(c, q0, q1)                                                        \
    { const u16* s_ = sp ? sA_lo : sA_hi;                                     \
      q0 = *(const short8*)(s_ + (size_t)sh * N + (c) * 32 + sseg);           \
      q1 = *(const short8*)(s_ + (size_t)(sh + 64) * N + (c) * 32 + sseg); }

#define LDB(c, q0, q1)                                                        \
    { const u16* s_ = sp ? WeT_lo : WeT_hi;                                   \
      q0 = *(const short8*)(s_ + (size_t)sh * H + (c) * 32 + sseg);           \
      q1 = *(const short8*)(s_ + (size_t)(sh + 64) * H + (c) * 32 + sseg); }

#define LDC(c, q0, q1)                                                        \
    { const u16* s_ = sp ? UwT_lo : UwT_hi;                                   \
      q0 = *(const short8*)(s_ + (size_t)sh * 2 * H + (c) * 32 + sseg);       \
      q1 = *(const short8*)(s_ + (size_t)(sh + 64) * 2 * H + (c) * 32 + sseg); }

#define LDD(c, q0, q1)                                                        \
    { const u16* s_ = sp ? W1T_lo : W1T_hi;                                   \
      q0 = *(const short8*)(s_ + (size_t)sh * 256 + (c) * 32 + sseg);         \
      q1 = *(const short8*)(s_ + (size_t)sh * 256 + 128 + (c) * 32 + sseg); }

#define COMPA(c, buf)                                                           \
    { short8 am = *(const short8*)&smask[lrow][(c) * 32 + kg8];                 \
      short8 bh = *(const short8*)&sbt[buf][0][cb + lrow][kg8];                 \
      short8 bl = *(const short8*)&sbt[buf][1][cb + lrow][kg8];                 \
      acc = __builtin_amdgcn_mfma_f32_16x16x32_bf16(am, bh, acc, 0, 0, 0);      \
      acc = __builtin_amdgcn_mfma_f32_16x16x32_bf16(am, bl, acc, 0, 0, 0); }

#define COMPB(c, buf)                                                           \
    { short8 ah = *(const short8*)&sagg_hi[lrow][(c) * 32 + kg8];               \
      short8 al = *(const short8*)&sagg_lo[lrow][(c) * 32 + kg8];               \
      short8 bh = *(const short8*)&sbt[buf][0][cb + lrow][kg8];                 \
      short8 bl = *(const short8*)&sbt[buf][1][cb + lrow][kg8];                 \
      acc = __builtin_amdgcn_mfma_f32_16x16x32_bf16(ah, bh, acc, 0, 0, 0);      \
      acc = __builtin_amdgcn_mfma_f32_16x16x32_bf16(ah, bl, acc, 0, 0, 0);      \
      acc = __builtin_amdgcn_mfma_f32_16x16x32_bf16(al, bh, acc, 0, 0, 0); }

#define COMPC(c, buf)                                                           \
    { int kc = ((c) & 3) * 32 + kg8; short8 ah, al;                             \
      if ((c) < 4) { ah = *(const short8*)&semb_hi[lrow][kc];                   \
                     al = *(const short8*)&semb_lo[lrow][kc]; }                 \
      else         { ah = *(const short8*)&smsg_hi[lrow][kc];                   \
                     al = *(const short8*)&smsg_lo[lrow][kc]; }                 \
      short8 bh = *(const short8*)&sbt[buf][0][cb + lrow][kg8];                 \
      short8 bl = *(const short8*)&sbt[buf][1][cb + lrow][kg8];                 \
      acc = __builtin_amdgcn_mfma_f32_16x16x32_bf16(ah, bh, acc, 0, 0, 0);      \
      acc = __builtin_amdgcn_mfma_f32_16x16x32_bf16(ah, bl, acc, 0, 0, 0);      \
      acc = __builtin_amdgcn_mfma_f32_16x16x32_bf16(al, bh, acc, 0, 0, 0); }

#define COMPD(c, buf)                                                           \
    { short8 ah = *(const short8*)&sagg_hi[lrow][(c) * 32 + kg8];               \
      short8 al = *(const short8*)&sagg_lo[lrow][(c) * 32 + kg8];               \
      short8 bh = *(const short8*)&sbt[buf][0][br][kg8];                        \
      short8 bl = *(const short8*)&sbt[buf][1][br][kg8];                        \
      acc = __builtin_amdgcn_mfma_f32_16x16x32_bf16(ah, bh, acc, 0, 0, 0);      \
      acc = __builtin_amdgcn_mfma_f32_16x16x32_bf16(ah, bl, acc, 0, 0, 0);      \
      acc = __builtin_amdgcn_mfma_f32_16x16x32_bf16(al, bh, acc, 0, 0, 0); }

    // Phase A
    f32x4 acc = {0.f, 0.f, 0.f, 0.f};
    PIPE(8, LDA, COMPA)
#pragma unroll
    for (int r = 0; r < 4; ++r) {
        float v = acc[r];
        u16 h = f2bf(v);
        sagg_hi[rb + r][cb + lrow] = h;
        sagg_lo[rb + r][cb + lrow] = f2bf(v - bf2f(h));
    }

    // Phase B
    acc = (f32x4){0.f, 0.f, 0.f, 0.f};
    PIPE(4, LDB, COMPB)
    {
        int hp = cb + lrow;
        float w0 = mwl[(H + 0) * H + hp];
        float w1 = mwl[(H + 1) * H + hp];
        float w2 = mwl[(H + 2) * H + hp];
        float mb = mbl[hp];
#pragma unroll
        for (int r = 0; r < 4; ++r) {
            int jl = j0 + rb + r;
            float v = acc[r] + deg[jl] * mb
                    + sragg[rb + r][0] * w0 + sragg[rb + r][1] * w1
                    + sragg[rb + r][2] * w2;
            u16 h = f2bf(v);
            smsg_hi[rb + r][hp] = h;
            smsg_lo[rb + r][hp] = f2bf(v - bf2f(h));
        }
    }

    // Phase C
    acc = (f32x4){0.f, 0.f, 0.f, 0.f};
    PIPE(8, LDC, COMPC)
    {
        float ub = ubl[cb + lrow];
#pragma unroll
        for (int r = 0; r < 4; ++r) {
            float v = fmaxf(acc[r] + ub, 0.f);
            if constexpr (LAST) {
                u16 h = f2bf(v);
                sagg_hi[rb + r][cb + lrow] = h;
                sagg_lo[rb + r][cb + lrow] = f2bf(v - bf2f(h));
            } else {
                sout[rb + r][cb + lrow] = v;
            }
        }
    }
    __syncthreads();

    if constexpr (!LAST) {
        {
            int row = t >> 5, h0 = (t & 31) * 4;
            int gr = gb + j0 + row;
            float4 v = *(const float4*)&sout[row][h0];
            float xs[4] = {v.x, v.y, v.z, v.w};
            short4v ph, pl;
#pragma unroll
            for (int c = 0; c < 4; ++c) {
                u16 h = f2bf(xs[c]);
                ph[c] = (short)h;
                pl[c] = (short)f2bf(xs[c] - bf2f(h));
            }
            *(short4v*)&oR_hi[(size_t)gr * H + h0] = ph;
            *(short4v*)&oR_lo[(size_t)gr * H + h0] = pl;
        }
        {
            int hh = t >> 2, jj = (t & 3) * 4;
            short4v th, tl;
#pragma unroll
            for (int r = 0; r < 4; ++r) {
                float x = sout[jj + r][hh];
                u16 h = f2bf(x);
                th[r] = (short)h;
                tl[r] = (short)f2bf(x - bf2f(h));
            }
            size_t o = (size_t)b * H * N + (size_t)hh * N + j0 + jj;
            *(short4v*)&oT_hi[o] = th;
            *(short4v*)&oT_lo[o] = tl;
        }
    } else {
        const int br = ((wave >= 4) ? 64 : 0) + (wave & 3) * 16 + lrow;
        acc = (f32x4){0.f, 0.f, 0.f, 0.f};
        PIPE(4, LDD, COMPD)
#pragma unroll
        for (int r = 0; r < 4; ++r) sout[rb + r][br] = acc[r];
        __syncthreads();
        int row = t >> 5, c0 = (t & 31) * 4;
        int gr = gb + j0 + row;
        float4 v = *(const float4*)&sout[row][c0];
        if (c0 < 64) *(float4*)&hi_out[(size_t)gr * FH + c0] = v;
        else         *(float4*)&hj_out[(size_t)gr * FH + (c0 - 64)] = v;
    }
#undef WRX
#undef LDA
#undef LDB
#undef LDC
#undef LDD
#undef COMPA
#undef COMPB
#undef COMPC
#undef COMPD
}

// ---------------------------------------------------------------------------
// k_final: tile 8(i) x 32(j) per block, 256 thr. (R6 body.)
__global__ __launch_bounds__(256) void k_final(
    const float* __restrict__ hi, const float* __restrict__ hj,
    const float* __restrict__ e0p, const float* __restrict__ e1p,
    const float* __restrict__ e2p, const float* __restrict__ temporal,
    const float* __restrict__ W1, const float* __restrict__ b1,
    const float* __restrict__ W2, const float* __restrict__ b2,
    float* __restrict__ flows) {
    __shared__ float his[8][FH];
    __shared__ float hjs[32][FH + 2];
    __shared__ float wr0[FH], wr1[FH], wr2[FH];
    __shared__ float wt0[FH], wt1[FH], wt2[FH], wt3[FH], bb[FH], w2s[FH];
    int blk = blockIdx.x;
    int jt = blk & 7, it = (blk >> 3) & 31, b = blk >> 8;
    int tid = threadIdx.x;
#pragma unroll
    for (int u = 0; u < 2; ++u) {
        int idx = u * 256 + tid;
        his[idx >> 6][idx & 63] = hi[((size_t)(b * N) + it * 8 + (idx >> 6)) * FH + (idx & 63)];
    }
#pragma unroll
    for (int u = 0; u < 8; ++u) {
        int idx = u * 256 + tid;
        hjs[idx >> 6][idx & 63] = hj[((size_t)(b * N) + jt * 32 + (idx >> 6)) * FH + (idx & 63)];
    }
    {
        int f = tid & 63, g = tid >> 6;
        if (g == 0) { wr0[f] = W1[(2 * H + 0) * FH + f]; wt0[f] = W1[(2 * H + 3) * FH + f]; bb[f] = b1[f]; }
        if (g == 1) { wr1[f] = W1[(2 * H + 1) * FH + f]; wt1[f] = W1[(2 * H + 4) * FH + f]; w2s[f] = W2[f]; }
        if (g == 2) { wr2[f] = W1[(2 * H + 2) * FH + f]; wt2[f] = W1[(2 * H + 5) * FH + f]; }
        if (g == 3) { wt3[f] = W1[(2 * H + 6) * FH + f]; }
    }
    __syncthreads();
    int ti = tid >> 5, tj = tid & 31;
    int i = it * 8 + ti, j = jt * 32 + tj;
    size_t pij = ((size_t)(b * N) + i) * N + j;
    float e0 = e0p[pij], e1 = e1p[pij], e2 = e2p[pij];
    float4 tf = *(const float4*)(temporal + pij * TD);
    float acc = 0.f;
#pragma unroll 8
    for (int f = 0; f < FH; ++f) {
        float v = his[ti][f] + hjs[tj][f] + bb[f]
                + e0 * wr0[f] + e1 * wr1[f] + e2 * wr2[f]
                + tf.x * wt0[f] + tf.y * wt1[f] + tf.z * wt2[f] + tf.w * wt3[f];
        acc += fmaxf(v, 0.f) * w2s[f];
    }
    flows[pij] = fmaxf(acc + b2[0], 0.f);
}

// ---------------------------------------------------------------------------
extern "C" void kernel_launch(void* const* d_in, const int* in_sizes, int n_in,
                              void* d_out, int out_size, void* d_ws, size_t ws_size,
                              hipStream_t stream) {
    const float* nf       = (const float*)d_in[0];
    const float* edge     = (const float*)d_in[1];
    const float* temporal = (const float*)d_in[2];
    const int*   adj      = (const int*)d_in[3];
    const float* W_emb    = (const float*)d_in[4];
    const float* b_emb    = (const float*)d_in[5];
    const float* msg_W    = (const float*)d_in[6];
    const float* msg_b    = (const float*)d_in[7];
    const float* upd_W    = (const float*)d_in[8];
    const float* upd_b    = (const float*)d_in[9];
    const float* W1       = (const float*)d_in[10];
    const float* b1       = (const float*)d_in[11];
    const float* W2       = (const float*)d_in[12];
    const float* b2       = (const float*)d_in[13];
    float* out = (float*)d_out;
    (void)in_sizes; (void)n_in; (void)out_size; (void)ws_size;

    char* p = (char*)d_ws;
    auto take = [&](size_t bytes) { char* r = p; p += (bytes + 255) & ~(size_t)255; return r; };
    float* deg   = (float*)take(256 * 4);
    float* ragg  = (float*)take((size_t)M * 3 * 4);
    float* e0p   = (float*)take((size_t)B * N * N * 4);
    float* e1p   = (float*)take((size_t)B * N * N * 4);
    float* e2p   = (float*)take((size_t)B * N * N * 4);
    float* rp0   = (float*)take((size_t)B * N * N * 4);
    float* rp1   = (float*)take((size_t)B * N * N * 4);
    float* rp2   = (float*)take((size_t)B * N * N * 4);
    float* hi    = (float*)take((size_t)M * FH * 4);
    float* hj    = (float*)take((size_t)M * FH * 4);
    u16* eRhA = (u16*)take((size_t)M * H * 2);
    u16* eRlA = (u16*)take((size_t)M * H * 2);
    u16* eThA = (u16*)take((size_t)M * H * 2);
    u16* eTlA = (u16*)take((size_t)M * H * 2);
    u16* eRhB = (u16*)take((size_t)M * H * 2);
    u16* eRlB = (u16*)take((size_t)M * H * 2);
    u16* eThB = (u16*)take((size_t)M * H * 2);
    u16* eTlB = (u16*)take((size_t)M * H * 2);
    u16* WeTh = (u16*)take(3 * 16384 * 2);
    u16* WeTl = (u16*)take(3 * 16384 * 2);
    u16* UwTh = (u16*)take(3 * 32768 * 2);
    u16* UwTl = (u16*)take(3 * 32768 * 2);
    u16* W1Th = (u16*)take(16384 * 2);
    u16* W1Tl = (u16*)take(16384 * 2);

    for (int r = 0; r < REPS; ++r)
        k_setup<<<3072, 256, 0, stream>>>(edge, adj, nf, W_emb, b_emb,
                                          msg_W, upd_W, W1,
                                          e0p, e1p, e2p, rp0, rp1, rp2, deg,
                                          WeTh, WeTl, UwTh, UwTl, W1Th, W1Tl,
                                          eRhA, eRlA, eThA, eTlA);

    const int mwS = (H + 3) * H;
    for (int r = 0; r < REPS; ++r)
        k_layer<true, false><<<128, 512, 0, stream>>>(
            eRhA, eRlA, eThA, eTlA, adj, rp0, rp1, rp2, ragg, deg,
            WeTh + 0 * 16384, WeTl + 0 * 16384, msg_W + 0 * mwS, msg_b + 0 * H,
            UwTh + 0 * 32768, UwTl + 0 * 32768, upd_b + 0 * H,
            eRhB, eRlB, eThB, eTlB, W1Th, W1Tl, hi, hj);
    for (int r = 0; r < REPS; ++r)
        k_layer<false, false><<<128, 512, 0, stream>>>(
            eRhB, eRlB, eThB, eTlB, adj, rp0, rp1, rp2, ragg, deg,
            WeTh + 1 * 16384, WeTl + 1 * 16384, msg_W + 1 * mwS, msg_b + 1 * H,
            UwTh + 1 * 32768, UwTl + 1 * 32768, upd_b + 1 * H,
            eRhA, eRlA, eThA, eTlA, W1Th, W1Tl, hi, hj);
    for (int r = 0; r < REPS; ++r)
        k_layer<false, true><<<128, 512, 0, stream>>>(
            eRhA, eRlA, eThA, eTlA, adj, rp0, rp1, rp2, ragg, deg,
            WeTh + 2 * 16384, WeTl + 2 * 16384, msg_W + 2 * mwS, msg_b + 2 * H,
            UwTh + 2 * 32768, UwTl + 2 * 32768, upd_b + 2 * H,
            eRhB, eRlB, eThB, eTlB, W1Th, W1Tl, hi, hj);

    for (int r = 0; r < REPS; ++r)
        k_final<<<2048, 256, 0, stream>>>(hi, hj, e0p, e1p, e2p, temporal,
                                          W1, b1, W2, b2, out);
}

// Round 12
// 363.441 us; speedup vs baseline: 1.3899x; 1.3899x over previous
//
#include <hip/hip_runtime.h>

#define B 8
#define N 256
#define H 128
#define NF 6
#define EF 15
#define TD 4
#define FH 64
#define M (B*N)

// R12 NOTE: bodies are the R6 (73.8 us) versions wrapped in an IN-KERNEL
// repeat loop (IREPS). Per-block work is idempotent, so output is unchanged;
// per-DISPATCH duration rises ~8x so all 5 kernels surface in the rocprof
// top-5 with their counters. Remove the loops after reading the breakdown.
#define IREPS 8

typedef unsigned short u16;
using short8  = __attribute__((ext_vector_type(8))) short;
using short4v = __attribute__((ext_vector_type(4))) short;
using f32x4   = __attribute__((ext_vector_type(4))) float;

__device__ __forceinline__ u16 f2bf(float x) {
    unsigned u = __float_as_uint(x);
    u += 0x7fffu + ((u >> 16) & 1u);
    return (u16)(u >> 16);
}
__device__ __forceinline__ float bf2f(u16 h) {
    return __uint_as_float(((unsigned)h) << 16);
}

// ---------------------------------------------------------------------------
// Depth-2 staging pipeline (R6).
#define PIPE(NC, LD, COMP)                          \
    LD(0, pA0, pA1);                                \
    LD(1, pB0, pB1);                                \
    WRX(0, pA0, pA1);                               \
    __syncthreads();                                \
    _Pragma("unroll")                               \
    for (int c = 0; c < (NC); c += 2) {             \
        WRX(1, pB0, pB1);                           \
        if (c + 2 < (NC)) LD(c + 2, pA0, pA1);      \
        COMP(c, 0);                                 \
        __syncthreads();                            \
        if (c + 2 < (NC)) WRX(0, pA0, pA1);         \
        if (c + 3 < (NC)) LD(c + 3, pB0, pB1);      \
        COMP(c + 1, 1);                             \
        __syncthreads();                            \
    }

// ---------------------------------------------------------------------------
// k_setup: role split by blockIdx.x (grid 3072, 256 thr). (R6 body + reps.)
__global__ __launch_bounds__(256) void k_setup(
    const float* __restrict__ edge, const int* __restrict__ adj,
    const float* __restrict__ nf, const float* __restrict__ Wemb,
    const float* __restrict__ bemb,
    const float* __restrict__ msg_W, const float* __restrict__ upd_W,
    const float* __restrict__ W1,
    float* __restrict__ e0p, float* __restrict__ e1p, float* __restrict__ e2p,
    float* __restrict__ rp0, float* __restrict__ rp1, float* __restrict__ rp2,
    float* __restrict__ deg,
    u16* __restrict__ WeTh, u16* __restrict__ WeTl,
    u16* __restrict__ UwTh, u16* __restrict__ UwTl,
    u16* __restrict__ W1Th, u16* __restrict__ W1Tl,
    u16* __restrict__ eRh, u16* __restrict__ eRl,
    u16* __restrict__ eTh, u16* __restrict__ eTl)
{
    __shared__ __align__(16) float smem[3848];
    __shared__ float red[4];
    const int t = threadIdx.x;
    const int blk = blockIdx.x;

#pragma unroll 1
    for (int rep = 0; rep < IREPS; ++rep) {
    __syncthreads();   // protect smem reuse across reps

    if (blk < 2048) {
        const int i = blk & 255;
        const float* src = edge + (size_t)blk * (N * EF);
        float4* s4 = (float4*)smem;
#pragma unroll
        for (int u = 0; u < 4; ++u) {
            int idx = t + u * 256;
            if (idx < (N * EF) / 4) s4[idx] = *(const float4*)(src + idx * 4);
        }
        __syncthreads();
        const int j = t;
        float e0 = smem[j * EF + 12];
        float e1 = smem[j * EF + 13];
        float e2 = smem[j * EF + 14];
        size_t base = (size_t)blk * N + j;
        e0p[base] = e0; e1p[base] = e1; e2p[base] = e2;
        float m = (adj[j * N + i] > 0) ? 1.f : 0.f;
        rp0[base] = m * e0; rp1[base] = m * e1; rp2[base] = m * e2;
    } else if (blk < 2688) {
        int idx = (blk - 2048) * 256 + t;
        float v; u16 *dh, *dl; int d;
        if (idx < 3 * 16384) {
            int l = idx / 16384, r = idx & 16383;
            int c = r >> 7, h = r & 127;
            v = msg_W[l * ((H + 3) * H) + h * H + c];
            dh = WeTh; dl = WeTl; d = idx;
        } else if (idx < 3 * 16384 + 3 * 32768) {
            int r0 = idx - 3 * 16384;
            int l = r0 / 32768, r = r0 & 32767;
            int c = r >> 8, k = r & 255;
            v = upd_W[l * (2 * H * H) + k * H + c];
            dh = UwTh; dl = UwTl; d = r0;
        } else {
            int r0 = idx - 3 * 16384 - 3 * 32768;
            int f = r0 >> 8, k = r0 & 255;
            v = W1[k * FH + f];
            dh = W1Th; dl = W1Tl; d = r0;
        }
        u16 h = f2bf(v);
        dh[d] = h;
        dl[d] = f2bf(v - bf2f(h));
    } else if (blk < 2816) {
        int tile = blk - 2688;
        float (*sout)[132] = (float(*)[132])smem;
        {
            int row = t >> 4, h0 = (t & 15) * 8;
            int gr = tile * 16 + row;
            float xv[NF];
#pragma unroll
            for (int k = 0; k < NF; ++k) xv[k] = nf[gr * NF + k];
#pragma unroll
            for (int c = 0; c < 8; ++c) {
                float a = bemb[h0 + c];
#pragma unroll
                for (int k = 0; k < NF; ++k) a += xv[k] * Wemb[k * H + h0 + c];
                sout[row][h0 + c] = fmaxf(a, 0.f);
            }
        }
        __syncthreads();
        {
            int row = t >> 4, h0 = (t & 15) * 8;
            int gr = tile * 16 + row;
            short8 ph, pl;
#pragma unroll
            for (int c = 0; c < 8; ++c) {
                float x = sout[row][h0 + c];
                u16 h = f2bf(x);
                ph[c] = (short)h;
                pl[c] = (short)f2bf(x - bf2f(h));
            }
            *(short8*)&eRh[(size_t)gr * H + h0] = ph;
            *(short8*)&eRl[(size_t)gr * H + h0] = pl;
        }
        {
            int hh = t >> 1, jj = (t & 1) * 8;
            short8 th, tl;
#pragma unroll
            for (int r = 0; r < 8; ++r) {
                float x = sout[jj + r][hh];
                u16 h = f2bf(x);
                th[r] = (short)h;
                tl[r] = (short)f2bf(x - bf2f(h));
            }
            size_t o = (size_t)(tile >> 4) * H * N + (size_t)hh * N + ((tile & 15) * 16) + jj;
            *(short8*)&eTh[o] = th;
            *(short8*)&eTl[o] = tl;
        }
    } else {
        int jr = blk - 2816;
        float v = (adj[jr * N + t] > 0) ? 1.f : 0.f;
        for (int o = 32; o > 0; o >>= 1) v += __shfl_down(v, o);
        if ((t & 63) == 0) red[t >> 6] = v;
        __syncthreads();
        if (t == 0) deg[jr] = red[0] + red[1] + red[2] + red[3];
    }
    }   // rep
}

// ---------------------------------------------------------------------------
// k_layer: MFMA bf16 hi/lo-split fused GNN layer. (R6 body + reps.)
template <bool FIRST, bool LAST>
__global__ __launch_bounds__(512) void k_layer(
    const u16* __restrict__ embR_hi, const u16* __restrict__ embR_lo,
    const u16* __restrict__ embT_hi, const u16* __restrict__ embT_lo,
    const int* __restrict__ adj,
    const float* __restrict__ rp0, const float* __restrict__ rp1,
    const float* __restrict__ rp2, float* __restrict__ ragg,
    const float* __restrict__ deg,
    const u16* __restrict__ WeT_hi, const u16* __restrict__ WeT_lo,
    const float* __restrict__ mwl, const float* __restrict__ mbl,
    const u16* __restrict__ UwT_hi, const u16* __restrict__ UwT_lo,
    const float* __restrict__ ubl,
    u16* __restrict__ oR_hi, u16* __restrict__ oR_lo,
    u16* __restrict__ oT_hi, u16* __restrict__ oT_lo,
    const u16* __restrict__ W1T_hi, const u16* __restrict__ W1T_lo,
    float* __restrict__ hi_out, float* __restrict__ hj_out)
{
    __shared__ __align__(16) u16 sbt[2][2][128][40];
    __shared__ __align__(16) u16 smask[16][264];
    __shared__ __align__(16) u16 semb_hi[16][136], semb_lo[16][136];
    __shared__ __align__(16) u16 sagg_hi[16][136], sagg_lo[16][136];
    __shared__ __align__(16) u16 smsg_hi[16][136], smsg_lo[16][136];
    __shared__ __align__(16) float sout[16][132];
    __shared__ float sragg[16][4];

    const int t = threadIdx.x;
    const int wave = t >> 6, lane = t & 63;
    const int lrow = lane & 15;
    const int kg8  = (lane >> 4) * 8;
    const int rb   = (lane >> 4) * 4;
    const int cb   = wave * 16;
    const int blk  = blockIdx.x;
    const int b    = blk >> 4, tile = blk & 15;
    const int j0   = tile * 16;
    const int gb   = b * N;

    const int sp = t >> 8, task = t & 255;
    const int sh = task >> 2, sseg = (task & 3) * 8;

    short8 pA0, pA1, pB0, pB1;

#pragma unroll 1
    for (int rep = 0; rep < IREPS; ++rep) {
    __syncthreads();   // protect shared reuse across reps

    {
        int j = t >> 5, i0 = (t & 31) * 8;
        int4 a0 = *(const int4*)(adj + (j0 + j) * N + i0);
        int4 a1 = *(const int4*)(adj + (j0 + j) * N + i0 + 4);
        short8 mrow;
        mrow[0] = (a0.x > 0) ? (short)0x3F80 : (short)0;
        mrow[1] = (a0.y > 0) ? (short)0x3F80 : (short)0;
        mrow[2] = (a0.z > 0) ? (short)0x3F80 : (short)0;
        mrow[3] = (a0.w > 0) ? (short)0x3F80 : (short)0;
        mrow[4] = (a1.x > 0) ? (short)0x3F80 : (short)0;
        mrow[5] = (a1.y > 0) ? (short)0x3F80 : (short)0;
        mrow[6] = (a1.z > 0) ? (short)0x3F80 : (short)0;
        mrow[7] = (a1.w > 0) ? (short)0x3F80 : (short)0;
        *(short8*)&smask[j][i0] = mrow;
        int h0 = (t & 31) * 4;
        *(short4v*)&semb_hi[j][h0] = *(const short4v*)&embR_hi[(size_t)(gb + j0 + j) * H + h0];
        *(short4v*)&semb_lo[j][h0] = *(const short4v*)&embR_lo[(size_t)(gb + j0 + j) * H + h0];
    }

    if constexpr (FIRST) {
        int j16 = t >> 5, ic = t & 31;
        int gj = gb + j0 + j16;
        float s0 = 0.f, s1 = 0.f, s2 = 0.f;
#pragma unroll
        for (int k = 0; k < 8; ++k) {
            size_t o = ((size_t)(gb + ic * 8 + k)) * N + (j0 + j16);
            s0 += rp0[o]; s1 += rp1[o]; s2 += rp2[o];
        }
        for (int o = 16; o > 0; o >>= 1) {
            s0 += __shfl_down(s0, o, 32);
            s1 += __shfl_down(s1, o, 32);
            s2 += __shfl_down(s2, o, 32);
        }
        if (ic == 0) {
            sragg[j16][0] = s0; sragg[j16][1] = s1; sragg[j16][2] = s2;
            float* rg = ragg + (size_t)gj * 3;
            rg[0] = s0; rg[1] = s1; rg[2] = s2;
        }
    } else {
        if (t < 48) sragg[t / 3][t % 3] = ragg[(size_t)(gb + j0 + t / 3) * 3 + (t % 3)];
    }

    const u16* sA_hi = embT_hi + (size_t)b * H * N;
    const u16* sA_lo = embT_lo + (size_t)b * H * N;

#define WRX(buf, q0, q1)                              \
    { *(short8*)&sbt[buf][sp][sh][sseg] = q0;         \
      *(short8*)&sbt[buf][sp][sh + 64][sseg] = q1; }

#define LDA(c, q0, q1)                                                        \
    { const u16* s_ = sp ? sA_lo : sA_hi;                                     \
      q0 = *(const short8*)(s_ + (size_t)sh * N + (c) * 32 + sseg);           \
      q1 = *(const short8*)(s_ + (size_t)(sh + 64) * N + (c) * 32 + sseg); }

#define LDB(c, q0, q1)                                                        \
    { const u16* s_ = sp ? WeT_lo : WeT_hi;                                   \
      q0 = *(const short8*)(s_ + (size_t)sh * H + (c) * 32 + sseg);           \
      q1 = *(const short8*)(s_ + (size_t)(sh + 64) * H + (c) * 32 + sseg); }

#define LDC(c, q0, q1)                                                        \
    { const u16* s_ = sp ? UwT_lo : UwT_hi;                                   \
      q0 = *(const short8*)(s_ + (size_t)sh * 2 * H + (c) * 32 + sseg);       \
      q1 = *(const short8*)(s_ + (size_t)(sh + 64) * 2 * H + (c) * 32 + sseg); }

#define LDD(c, q0, q1)                                                        \
    { const u16* s_ = sp ? W1T_lo : W1T_hi;                                   \
      q0 = *(const short8*)(s_ + (size_t)sh * 256 + (c) * 32 + sseg);         \
      q1 = *(const short8*)(s_ + (size_t)sh * 256 + 128 + (c) * 32 + sseg); }

#define COMPA(c, buf)                                                           \
    { short8 am = *(const short8*)&smask[lrow][(c) * 32 + kg8];                 \
      short8 bh = *(const short8*)&sbt[buf][0][cb + lrow][kg8];                 \
      short8 bl = *(const short8*)&sbt[buf][1][cb + lrow][kg8];                 \
      acc = __builtin_amdgcn_mfma_f32_16x16x32_bf16(am, bh, acc, 0, 0, 0);      \
      acc = __builtin_amdgcn_mfma_f32_16x16x32_bf16(am, bl, acc, 0, 0, 0); }

#define COMPB(c, buf)                                                           \
    { short8 ah = *(const short8*)&sagg_hi[lrow][(c) * 32 + kg8];               \
      short8 al = *(const short8*)&sagg_lo[lrow][(c) * 32 + kg8];               \
      short8 bh = *(const short8*)&sbt[buf][0][cb + lrow][kg8];                 \
      short8 bl = *(const short8*)&sbt[buf][1][cb + lrow][kg8];                 \
      acc = __builtin_amdgcn_mfma_f32_16x16x32_bf16(ah, bh, acc, 0, 0, 0);      \
      acc = __builtin_amdgcn_mfma_f32_16x16x32_bf16(ah, bl, acc, 0, 0, 0);      \
      acc = __builtin_amdgcn_mfma_f32_16x16x32_bf16(al, bh, acc, 0, 0, 0); }

#define COMPC(c, buf)                                                           \
    { int kc = ((c) & 3) * 32 + kg8; short8 ah, al;                             \
      if ((c) < 4) { ah = *(const short8*)&semb_hi[lrow][kc];                   \
                     al = *(const short8*)&semb_lo[lrow][kc]; }                 \
      else         { ah = *(const short8*)&smsg_hi[lrow][kc];                   \
                     al = *(const short8*)&smsg_lo[lrow][kc]; }                 \
      short8 bh = *(const short8*)&sbt[buf][0][cb + lrow][kg8];                 \
      short8 bl = *(const short8*)&sbt[buf][1][cb + lrow][kg8];                 \
      acc = __builtin_amdgcn_mfma_f32_16x16x32_bf16(ah, bh, acc, 0, 0, 0);      \
      acc = __builtin_amdgcn_mfma_f32_16x16x32_bf16(ah, bl, acc, 0, 0, 0);      \
      acc = __builtin_amdgcn_mfma_f32_16x16x32_bf16(al, bh, acc, 0, 0, 0); }

#define COMPD(c, buf)                                                           \
    { short8 ah = *(const short8*)&sagg_hi[lrow][(c) * 32 + kg8];               \
      short8 al = *(const short8*)&sagg_lo[lrow][(c) * 32 + kg8];               \
      short8 bh = *(const short8*)&sbt[buf][0][br][kg8];                        \
      short8 bl = *(const short8*)&sbt[buf][1][br][kg8];                        \
      acc = __builtin_amdgcn_mfma_f32_16x16x32_bf16(ah, bh, acc, 0, 0, 0);      \
      acc = __builtin_amdgcn_mfma_f32_16x16x32_bf16(ah, bl, acc, 0, 0, 0);      \
      acc = __builtin_amdgcn_mfma_f32_16x16x32_bf16(al, bh, acc, 0, 0, 0); }

    // Phase A
    f32x4 acc = {0.f, 0.f, 0.f, 0.f};
    PIPE(8, LDA, COMPA)
#pragma unroll
    for (int r = 0; r < 4; ++r) {
        float v = acc[r];
        u16 h = f2bf(v);
        sagg_hi[rb + r][cb + lrow] = h;
        sagg_lo[rb + r][cb + lrow] = f2bf(v - bf2f(h));
    }

    // Phase B
    acc = (f32x4){0.f, 0.f, 0.f, 0.f};
    PIPE(4, LDB, COMPB)
    {
        int hp = cb + lrow;
        float w0 = mwl[(H + 0) * H + hp];
        float w1 = mwl[(H + 1) * H + hp];
        float w2 = mwl[(H + 2) * H + hp];
        float mb = mbl[hp];
#pragma unroll
        for (int r = 0; r < 4; ++r) {
            int jl = j0 + rb + r;
            float v = acc[r] + deg[jl] * mb
                    + sragg[rb + r][0] * w0 + sragg[rb + r][1] * w1
                    + sragg[rb + r][2] * w2;
            u16 h = f2bf(v);
            smsg_hi[rb + r][hp] = h;
            smsg_lo[rb + r][hp] = f2bf(v - bf2f(h));
        }
    }

    // Phase C
    acc = (f32x4){0.f, 0.f, 0.f, 0.f};
    PIPE(8, LDC, COMPC)
    {
        float ub = ubl[cb + lrow];
#pragma unroll
        for (int r = 0; r < 4; ++r) {
            float v = fmaxf(acc[r] + ub, 0.f);
            if constexpr (LAST) {
                u16 h = f2bf(v);
                sagg_hi[rb + r][cb + lrow] = h;
                sagg_lo[rb + r][cb + lrow] = f2bf(v - bf2f(h));
            } else {
                sout[rb + r][cb + lrow] = v;
            }
        }
    }
    __syncthreads();

    if constexpr (!LAST) {
        {
            int row = t >> 5, h0 = (t & 31) * 4;
            int gr = gb + j0 + row;
            float4 v = *(const float4*)&sout[row][h0];
            float xs[4] = {v.x, v.y, v.z, v.w};
            short4v ph, pl;
#pragma unroll
            for (int c = 0; c < 4; ++c) {
                u16 h = f2bf(xs[c]);
                ph[c] = (short)h;
                pl[c] = (short)f2bf(xs[c] - bf2f(h));
            }
            *(short4v*)&oR_hi[(size_t)gr * H + h0] = ph;
            *(short4v*)&oR_lo[(size_t)gr * H + h0] = pl;
        }
        {
            int hh = t >> 2, jj = (t & 3) * 4;
            short4v th, tl;
#pragma unroll
            for (int r = 0; r < 4; ++r) {
                float x = sout[jj + r][hh];
                u16 h = f2bf(x);
                th[r] = (short)h;
                tl[r] = (short)f2bf(x - bf2f(h));
            }
            size_t o = (size_t)b * H * N + (size_t)hh * N + j0 + jj;
            *(short4v*)&oT_hi[o] = th;
            *(short4v*)&oT_lo[o] = tl;
        }
    } else {
        const int br = ((wave >= 4) ? 64 : 0) + (wave & 3) * 16 + lrow;
        acc = (f32x4){0.f, 0.f, 0.f, 0.f};
        PIPE(4, LDD, COMPD)
#pragma unroll
        for (int r = 0; r < 4; ++r) sout[rb + r][br] = acc[r];
        __syncthreads();
        int row = t >> 5, c0 = (t & 31) * 4;
        int gr = gb + j0 + row;
        float4 v = *(const float4*)&sout[row][c0];
        if (c0 < 64) *(float4*)&hi_out[(size_t)gr * FH + c0] = v;
        else         *(float4*)&hj_out[(size_t)gr * FH + (c0 - 64)] = v;
    }
#undef WRX
#undef LDA
#undef LDB
#undef LDC
#undef LDD
#undef COMPA
#undef COMPB
#undef COMPC
#undef COMPD
    }   // rep
}

// ---------------------------------------------------------------------------
// k_final: tile 8(i) x 32(j) per block, 256 thr. (R6 body + reps.)
__global__ __launch_bounds__(256) void k_final(
    const float* __restrict__ hi, const float* __restrict__ hj,
    const float* __restrict__ e0p, const float* __restrict__ e1p,
    const float* __restrict__ e2p, const float* __restrict__ temporal,
    const float* __restrict__ W1, const float* __restrict__ b1,
    const float* __restrict__ W2, const float* __restrict__ b2,
    float* __restrict__ flows) {
    __shared__ float his[8][FH];
    __shared__ float hjs[32][FH + 2];
    __shared__ float wr0[FH], wr1[FH], wr2[FH];
    __shared__ float wt0[FH], wt1[FH], wt2[FH], wt3[FH], bb[FH], w2s[FH];
    int blk = blockIdx.x;
    int jt = blk & 7, it = (blk >> 3) & 31, b = blk >> 8;
    int tid = threadIdx.x;

#pragma unroll 1
    for (int rep = 0; rep < IREPS; ++rep) {
    __syncthreads();   // protect shared reuse across reps
#pragma unroll
    for (int u = 0; u < 2; ++u) {
        int idx = u * 256 + tid;
        his[idx >> 6][idx & 63] = hi[((size_t)(b * N) + it * 8 + (idx >> 6)) * FH + (idx & 63)];
    }
#pragma unroll
    for (int u = 0; u < 8; ++u) {
        int idx = u * 256 + tid;
        hjs[idx >> 6][idx & 63] = hj[((size_t)(b * N) + jt * 32 + (idx >> 6)) * FH + (idx & 63)];
    }
    {
        int f = tid & 63, g = tid >> 6;
        if (g == 0) { wr0[f] = W1[(2 * H + 0) * FH + f]; wt0[f] = W1[(2 * H + 3) * FH + f]; bb[f] = b1[f]; }
        if (g == 1) { wr1[f] = W1[(2 * H + 1) * FH + f]; wt1[f] = W1[(2 * H + 4) * FH + f]; w2s[f] = W2[f]; }
        if (g == 2) { wr2[f] = W1[(2 * H + 2) * FH + f]; wt2[f] = W1[(2 * H + 5) * FH + f]; }
        if (g == 3) { wt3[f] = W1[(2 * H + 6) * FH + f]; }
    }
    __syncthreads();
    int ti = tid >> 5, tj = tid & 31;
    int i = it * 8 + ti, j = jt * 32 + tj;
    size_t pij = ((size_t)(b * N) + i) * N + j;
    float e0 = e0p[pij], e1 = e1p[pij], e2 = e2p[pij];
    float4 tf = *(const float4*)(temporal + pij * TD);
    float acc = 0.f;
#pragma unroll 8
    for (int f = 0; f < FH; ++f) {
        float v = his[ti][f] + hjs[tj][f] + bb[f]
                + e0 * wr0[f] + e1 * wr1[f] + e2 * wr2[f]
                + tf.x * wt0[f] + tf.y * wt1[f] + tf.z * wt2[f] + tf.w * wt3[f];
        acc += fmaxf(v, 0.f) * w2s[f];
    }
    flows[pij] = fmaxf(acc + b2[0], 0.f);
    __syncthreads();   // rep boundary: all reads of shared done before rewrite
    }   // rep
}

// ---------------------------------------------------------------------------
extern "C" void kernel_launch(void* const* d_in, const int* in_sizes, int n_in,
                              void* d_out, int out_size, void* d_ws, size_t ws_size,
                              hipStream_t stream) {
    const float* nf       = (const float*)d_in[0];
    const float* edge     = (const float*)d_in[1];
    const float* temporal = (const float*)d_in[2];
    const int*   adj      = (const int*)d_in[3];
    const float* W_emb    = (const float*)d_in[4];
    const float* b_emb    = (const float*)d_in[5];
    const float* msg_W    = (const float*)d_in[6];
    const float* msg_b    = (const float*)d_in[7];
    const float* upd_W    = (const float*)d_in[8];
    const float* upd_b    = (const float*)d_in[9];
    const float* W1       = (const float*)d_in[10];
    const float* b1       = (const float*)d_in[11];
    const float* W2       = (const float*)d_in[12];
    const float* b2       = (const float*)d_in[13];
    float* out = (float*)d_out;
    (void)in_sizes; (void)n_in; (void)out_size; (void)ws_size;

    char* p = (char*)d_ws;
    auto take = [&](size_t bytes) { char* r = p; p += (bytes + 255) & ~(size_t)255; return r; };
    float* deg   = (float*)take(256 * 4);
    float* ragg  = (float*)take((size_t)M * 3 * 4);
    float* e0p   = (float*)take((size_t)B * N * N * 4);
    float* e1p   = (float*)take((size_t)B * N * N * 4);
    float* e2p   = (float*)take((size_t)B * N * N * 4);
    float* rp0   = (float*)take((size_t)B * N * N * 4);
    float* rp1   = (float*)take((size_t)B * N * N * 4);
    float* rp2   = (float*)take((size_t)B * N * N * 4);
    float* hi    = (float*)take((size_t)M * FH * 4);
    float* hj    = (float*)take((size_t)M * FH * 4);
    u16* eRhA = (u16*)take((size_t)M * H * 2);
    u16* eRlA = (u16*)take((size_t)M * H * 2);
    u16* eThA = (u16*)take((size_t)M * H * 2);
    u16* eTlA = (u16*)take((size_t)M * H * 2);
    u16* eRhB = (u16*)take((size_t)M * H * 2);
    u16* eRlB = (u16*)take((size_t)M * H * 2);
    u16* eThB = (u16*)take((size_t)M * H * 2);
    u16* eTlB = (u16*)take((size_t)M * H * 2);
    u16* WeTh = (u16*)take(3 * 16384 * 2);
    u16* WeTl = (u16*)take(3 * 16384 * 2);
    u16* UwTh = (u16*)take(3 * 32768 * 2);
    u16* UwTl = (u16*)take(3 * 32768 * 2);
    u16* W1Th = (u16*)take(16384 * 2);
    u16* W1Tl = (u16*)take(16384 * 2);

    k_setup<<<3072, 256, 0, stream>>>(edge, adj, nf, W_emb, b_emb,
                                      msg_W, upd_W, W1,
                                      e0p, e1p, e2p, rp0, rp1, rp2, deg,
                                      WeTh, WeTl, UwTh, UwTl, W1Th, W1Tl,
                                      eRhA, eRlA, eThA, eTlA);

    const int mwS = (H + 3) * H;
    k_layer<true, false><<<128, 512, 0, stream>>>(
        eRhA, eRlA, eThA, eTlA, adj, rp0, rp1, rp2, ragg, deg,
        WeTh + 0 * 16384, WeTl + 0 * 16384, msg_W + 0 * mwS, msg_b + 0 * H,
        UwTh + 0 * 32768, UwTl + 0 * 32768, upd_b + 0 * H,
        eRhB, eRlB, eThB, eTlB, W1Th, W1Tl, hi, hj);
    k_layer<false, false><<<128, 512, 0, stream>>>(
        eRhB, eRlB, eThB, eTlB, adj, rp0, rp1, rp2, ragg, deg,
        WeTh + 1 * 16384, WeTl + 1 * 16384, msg_W + 1 * mwS, msg_b + 1 * H,
        UwTh + 1 * 32768, UwTl + 1 * 32768, upd_b + 1 * H,
        eRhA, eRlA, eThA, eTlA, W1Th, W1Tl, hi, hj);
    k_layer<false, true><<<128, 512, 0, stream>>>(
        eRhA, eRlA, eThA, eTlA, adj, rp0, rp1, rp2, ragg, deg,
        WeTh + 2 * 16384, WeTl + 2 * 16384, msg_W + 2 * mwS, msg_b + 2 * H,
        UwTh + 2 * 32768, UwTl + 2 * 32768, upd_b + 2 * H,
        eRhB, eRlB, eThB, eTlB, W1Th, W1Tl, hi, hj);

    k_final<<<2048, 256, 0, stream>>>(hi, hj, e0p, e1p, e2p, temporal,
                                      W1, b1, W2, b2, out);
}

// Round 13
// 67.321 us; speedup vs baseline: 7.5034x; 5.3986x over previous
//
#include <hip/hip_runtime.h>

#define B 8
#define N 256
#define H 128
#define NF 6
#define EF 15
#define TD 4
#define FH 64
#define M (B*N)

typedef unsigned short u16;
using short8  = __attribute__((ext_vector_type(8))) short;
using short4v = __attribute__((ext_vector_type(4))) short;
using f32x4   = __attribute__((ext_vector_type(4))) float;

__device__ __forceinline__ u16 f2bf(float x) {
    unsigned u = __float_as_uint(x);
    u += 0x7fffu + ((u >> 16) & 1u);
    return (u16)(u >> 16);
}
__device__ __forceinline__ float bf2f(u16 h) {
    return __uint_as_float(((unsigned)h) << 16);
}

// ---------------------------------------------------------------------------
// Depth-2 staging pipeline (R6).
#define PIPE(NC, LD, COMP)                          \
    LD(0, pA0, pA1);                                \
    LD(1, pB0, pB1);                                \
    WRX(0, pA0, pA1);                               \
    __syncthreads();                                \
    _Pragma("unroll")                               \
    for (int c = 0; c < (NC); c += 2) {             \
        WRX(1, pB0, pB1);                           \
        if (c + 2 < (NC)) LD(c + 2, pA0, pA1);      \
        COMP(c, 0);                                 \
        __syncthreads();                            \
        if (c + 2 < (NC)) WRX(0, pA0, pA1);         \
        if (c + 3 < (NC)) LD(c + 3, pB0, pB1);      \
        COMP(c + 1, 1);                             \
        __syncthreads();                            \
    }

// ---------------------------------------------------------------------------
// k_setup: role split by blockIdx.x (grid 3072, 256 thr). (R6 body, proven.)
__global__ __launch_bounds__(256) void k_setup(
    const float* __restrict__ edge, const int* __restrict__ adj,
    const float* __restrict__ nf, const float* __restrict__ Wemb,
    const float* __restrict__ bemb,
    const float* __restrict__ msg_W, const float* __restrict__ upd_W,
    const float* __restrict__ W1,
    float* __restrict__ e0p, float* __restrict__ e1p, float* __restrict__ e2p,
    float* __restrict__ rp0, float* __restrict__ rp1, float* __restrict__ rp2,
    float* __restrict__ deg,
    u16* __restrict__ WeTh, u16* __restrict__ WeTl,
    u16* __restrict__ UwTh, u16* __restrict__ UwTl,
    u16* __restrict__ W1Th, u16* __restrict__ W1Tl,
    u16* __restrict__ eRh, u16* __restrict__ eRl,
    u16* __restrict__ eTh, u16* __restrict__ eTl)
{
    __shared__ __align__(16) float smem[3848];
    __shared__ float red[4];
    const int t = threadIdx.x;
    const int blk = blockIdx.x;

    if (blk < 2048) {
        const int i = blk & 255;
        const float* src = edge + (size_t)blk * (N * EF);
        float4* s4 = (float4*)smem;
#pragma unroll
        for (int u = 0; u < 4; ++u) {
            int idx = t + u * 256;
            if (idx < (N * EF) / 4) s4[idx] = *(const float4*)(src + idx * 4);
        }
        __syncthreads();
        const int j = t;
        float e0 = smem[j * EF + 12];
        float e1 = smem[j * EF + 13];
        float e2 = smem[j * EF + 14];
        size_t base = (size_t)blk * N + j;
        e0p[base] = e0; e1p[base] = e1; e2p[base] = e2;
        float m = (adj[j * N + i] > 0) ? 1.f : 0.f;
        rp0[base] = m * e0; rp1[base] = m * e1; rp2[base] = m * e2;
    } else if (blk < 2688) {
        int idx = (blk - 2048) * 256 + t;
        float v; u16 *dh, *dl; int d;
        if (idx < 3 * 16384) {
            int l = idx / 16384, r = idx & 16383;
            int c = r >> 7, h = r & 127;
            v = msg_W[l * ((H + 3) * H) + h * H + c];
            dh = WeTh; dl = WeTl; d = idx;
        } else if (idx < 3 * 16384 + 3 * 32768) {
            int r0 = idx - 3 * 16384;
            int l = r0 / 32768, r = r0 & 32767;
            int c = r >> 8, k = r & 255;
            v = upd_W[l * (2 * H * H) + k * H + c];
            dh = UwTh; dl = UwTl; d = r0;
        } else {
            int r0 = idx - 3 * 16384 - 3 * 32768;
            int f = r0 >> 8, k = r0 & 255;
            v = W1[k * FH + f];
            dh = W1Th; dl = W1Tl; d = r0;
        }
        u16 h = f2bf(v);
        dh[d] = h;
        dl[d] = f2bf(v - bf2f(h));
    } else if (blk < 2816) {
        int tile = blk - 2688;
        float (*sout)[132] = (float(*)[132])smem;
        {
            int row = t >> 4, h0 = (t & 15) * 8;
            int gr = tile * 16 + row;
            float xv[NF];
#pragma unroll
            for (int k = 0; k < NF; ++k) xv[k] = nf[gr * NF + k];
#pragma unroll
            for (int c = 0; c < 8; ++c) {
                float a = bemb[h0 + c];
#pragma unroll
                for (int k = 0; k < NF; ++k) a += xv[k] * Wemb[k * H + h0 + c];
                sout[row][h0 + c] = fmaxf(a, 0.f);
            }
        }
        __syncthreads();
        {
            int row = t >> 4, h0 = (t & 15) * 8;
            int gr = tile * 16 + row;
            short8 ph, pl;
#pragma unroll
            for (int c = 0; c < 8; ++c) {
                float x = sout[row][h0 + c];
                u16 h = f2bf(x);
                ph[c] = (short)h;
                pl[c] = (short)f2bf(x - bf2f(h));
            }
            *(short8*)&eRh[(size_t)gr * H + h0] = ph;
            *(short8*)&eRl[(size_t)gr * H + h0] = pl;
        }
        {
            int hh = t >> 1, jj = (t & 1) * 8;
            short8 th, tl;
#pragma unroll
            for (int r = 0; r < 8; ++r) {
                float x = sout[jj + r][hh];
                u16 h = f2bf(x);
                th[r] = (short)h;
                tl[r] = (short)f2bf(x - bf2f(h));
            }
            size_t o = (size_t)(tile >> 4) * H * N + (size_t)hh * N + ((tile & 15) * 16) + jj;
            *(short8*)&eTh[o] = th;
            *(short8*)&eTl[o] = tl;
        }
    } else {
        int jr = blk - 2816;
        float v = (adj[jr * N + t] > 0) ? 1.f : 0.f;
        for (int o = 32; o > 0; o >>= 1) v += __shfl_down(v, o);
        if ((t & 63) == 0) red[t >> 6] = v;
        __syncthreads();
        if (t == 0) deg[jr] = red[0] + red[1] + red[2] + red[3];
    }
}

// ---------------------------------------------------------------------------
// k_layer: MFMA bf16 hi/lo-split fused GNN layer. (R6 body, proven.)
template <bool FIRST, bool LAST>
__global__ __launch_bounds__(512) void k_layer(
    const u16* __restrict__ embR_hi, const u16* __restrict__ embR_lo,
    const u16* __restrict__ embT_hi, const u16* __restrict__ embT_lo,
    const int* __restrict__ adj,
    const float* __restrict__ rp0, const float* __restrict__ rp1,
    const float* __restrict__ rp2, float* __restrict__ ragg,
    const float* __restrict__ deg,
    const u16* __restrict__ WeT_hi, const u16* __restrict__ WeT_lo,
    const float* __restrict__ mwl, const float* __restrict__ mbl,
    const u16* __restrict__ UwT_hi, const u16* __restrict__ UwT_lo,
    const float* __restrict__ ubl,
    u16* __restrict__ oR_hi, u16* __restrict__ oR_lo,
    u16* __restrict__ oT_hi, u16* __restrict__ oT_lo,
    const u16* __restrict__ W1T_hi, const u16* __restrict__ W1T_lo,
    float* __restrict__ hi_out, float* __restrict__ hj_out)
{
    __shared__ __align__(16) u16 sbt[2][2][128][40];
    __shared__ __align__(16) u16 smask[16][264];
    __shared__ __align__(16) u16 semb_hi[16][136], semb_lo[16][136];
    __shared__ __align__(16) u16 sagg_hi[16][136], sagg_lo[16][136];
    __shared__ __align__(16) u16 smsg_hi[16][136], smsg_lo[16][136];
    __shared__ __align__(16) float sout[16][132];
    __shared__ float sragg[16][4];

    const int t = threadIdx.x;
    const int wave = t >> 6, lane = t & 63;
    const int lrow = lane & 15;
    const int kg8  = (lane >> 4) * 8;
    const int rb   = (lane >> 4) * 4;
    const int cb   = wave * 16;
    const int blk  = blockIdx.x;
    const int b    = blk >> 4, tile = blk & 15;
    const int j0   = tile * 16;
    const int gb   = b * N;

    const int sp = t >> 8, task = t & 255;
    const int sh = task >> 2, sseg = (task & 3) * 8;

    short8 pA0, pA1, pB0, pB1;

    {
        int j = t >> 5, i0 = (t & 31) * 8;
        int4 a0 = *(const int4*)(adj + (j0 + j) * N + i0);
        int4 a1 = *(const int4*)(adj + (j0 + j) * N + i0 + 4);
        short8 mrow;
        mrow[0] = (a0.x > 0) ? (short)0x3F80 : (short)0;
        mrow[1] = (a0.y > 0) ? (short)0x3F80 : (short)0;
        mrow[2] = (a0.z > 0) ? (short)0x3F80 : (short)0;
        mrow[3] = (a0.w > 0) ? (short)0x3F80 : (short)0;
        mrow[4] = (a1.x > 0) ? (short)0x3F80 : (short)0;
        mrow[5] = (a1.y > 0) ? (short)0x3F80 : (short)0;
        mrow[6] = (a1.z > 0) ? (short)0x3F80 : (short)0;
        mrow[7] = (a1.w > 0) ? (short)0x3F80 : (short)0;
        *(short8*)&smask[j][i0] = mrow;
        int h0 = (t & 31) * 4;
        *(short4v*)&semb_hi[j][h0] = *(const short4v*)&embR_hi[(size_t)(gb + j0 + j) * H + h0];
        *(short4v*)&semb_lo[j][h0] = *(const short4v*)&embR_lo[(size_t)(gb + j0 + j) * H + h0];
    }

    if constexpr (FIRST) {
        int j16 = t >> 5, ic = t & 31;
        int gj = gb + j0 + j16;
        float s0 = 0.f, s1 = 0.f, s2 = 0.f;
#pragma unroll
        for (int k = 0; k < 8; ++k) {
            size_t o = ((size_t)(gb + ic * 8 + k)) * N + (j0 + j16);
            s0 += rp0[o]; s1 += rp1[o]; s2 += rp2[o];
        }
        for (int o = 16; o > 0; o >>= 1) {
            s0 += __shfl_down(s0, o, 32);
            s1 += __shfl_down(s1, o, 32);
            s2 += __shfl_down(s2, o, 32);
        }
        if (ic == 0) {
            sragg[j16][0] = s0; sragg[j16][1] = s1; sragg[j16][2] = s2;
            float* rg = ragg + (size_t)gj * 3;
            rg[0] = s0; rg[1] = s1; rg[2] = s2;
        }
    } else {
        if (t < 48) sragg[t / 3][t % 3] = ragg[(size_t)(gb + j0 + t / 3) * 3 + (t % 3)];
    }

    const u16* sA_hi = embT_hi + (size_t)b * H * N;
    const u16* sA_lo = embT_lo + (size_t)b * H * N;

#define WRX(buf, q0, q1)                              \
    { *(short8*)&sbt[buf][sp][sh][sseg] = q0;         \
      *(short8*)&sbt[buf][sp][sh + 64][sseg] = q1; }

#define LDA(c, q0, q1)                                                        \
    { const u16* s_ = sp ? sA_lo : sA_hi;                                     \
      q0 = *(const short8*)(s_ + (size_t)sh * N + (c) * 32 + sseg);           \
      q1 = *(const short8*)(s_ + (size_t)(sh + 64) * N + (c) * 32 + sseg); }

#define LDB(c, q0, q1)                                                        \
    { const u16* s_ = sp ? WeT_lo : WeT_hi;                                   \
      q0 = *(const short8*)(s_ + (size_t)sh * H + (c) * 32 + sseg);           \
      q1 = *(const short8*)(s_ + (size_t)(sh + 64) * H + (c) * 32 + sseg); }

#define LDC(c, q0, q1)                                                        \
    { const u16* s_ = sp ? UwT_lo : UwT_hi;                                   \
      q0 = *(const short8*)(s_ + (size_t)sh * 2 * H + (c) * 32 + sseg);       \
      q1 = *(const short8*)(s_ + (size_t)(sh + 64) * 2 * H + (c) * 32 + sseg); }

#define LDD(c, q0, q1)                                                        \
    { const u16* s_ = sp ? W1T_lo : W1T_hi;                                   \
      q0 = *(const short8*)(s_ + (size_t)sh * 256 + (c) * 32 + sseg);         \
      q1 = *(const short8*)(s_ + (size_t)sh * 256 + 128 + (c) * 32 + sseg); }

#define COMPA(c, buf)                                                           \
    { short8 am = *(const short8*)&smask[lrow][(c) * 32 + kg8];                 \
      short8 bh = *(const short8*)&sbt[buf][0][cb + lrow][kg8];                 \
      short8 bl = *(const short8*)&sbt[buf][1][cb + lrow][kg8];                 \
      acc = __builtin_amdgcn_mfma_f32_16x16x32_bf16(am, bh, acc, 0, 0, 0);      \
      acc = __builtin_amdgcn_mfma_f32_16x16x32_bf16(am, bl, acc, 0, 0, 0); }

#define COMPB(c, buf)                                                           \
    { short8 ah = *(const short8*)&sagg_hi[lrow][(c) * 32 + kg8];               \
      short8 al = *(const short8*)&sagg_lo[lrow][(c) * 32 + kg8];               \
      short8 bh = *(const short8*)&sbt[buf][0][cb + lrow][kg8];                 \
      short8 bl = *(const short8*)&sbt[buf][1][cb + lrow][kg8];                 \
      acc = __builtin_amdgcn_mfma_f32_16x16x32_bf16(ah, bh, acc, 0, 0, 0);      \
      acc = __builtin_amdgcn_mfma_f32_16x16x32_bf16(ah, bl, acc, 0, 0, 0);      \
      acc = __builtin_amdgcn_mfma_f32_16x16x32_bf16(al, bh, acc, 0, 0, 0); }

#define COMPC(c, buf)                                                           \
    { int kc = ((c) & 3) * 32 + kg8; short8 ah, al;                             \
      if ((c) < 4) { ah = *(const short8*)&semb_hi[lrow][kc];                   \
                     al = *(const short8*)&semb_lo[lrow][kc]; }                 \
      else         { ah = *(const short8*)&smsg_hi[lrow][kc];                   \
                     al = *(const short8*)&smsg_lo[lrow][kc]; }                 \
      short8 bh = *(const short8*)&sbt[buf][0][cb + lrow][kg8];                 \
      short8 bl = *(const short8*)&sbt[buf][1][cb + lrow][kg8];                 \
      acc = __builtin_amdgcn_mfma_f32_16x16x32_bf16(ah, bh, acc, 0, 0, 0);      \
      acc = __builtin_amdgcn_mfma_f32_16x16x32_bf16(ah, bl, acc, 0, 0, 0);      \
      acc = __builtin_amdgcn_mfma_f32_16x16x32_bf16(al, bh, acc, 0, 0, 0); }

#define COMPD(c, buf)                                                           \
    { short8 ah = *(const short8*)&sagg_hi[lrow][(c) * 32 + kg8];               \
      short8 al = *(const short8*)&sagg_lo[lrow][(c) * 32 + kg8];               \
      short8 bh = *(const short8*)&sbt[buf][0][br][kg8];                        \
      short8 bl = *(const short8*)&sbt[buf][1][br][kg8];                        \
      acc = __builtin_amdgcn_mfma_f32_16x16x32_bf16(ah, bh, acc, 0, 0, 0);      \
      acc = __builtin_amdgcn_mfma_f32_16x16x32_bf16(ah, bl, acc, 0, 0, 0);      \
      acc = __builtin_amdgcn_mfma_f32_16x16x32_bf16(al, bh, acc, 0, 0, 0); }

    // Phase A
    f32x4 acc = {0.f, 0.f, 0.f, 0.f};
    PIPE(8, LDA, COMPA)
#pragma unroll
    for (int r = 0; r < 4; ++r) {
        float v = acc[r];
        u16 h = f2bf(v);
        sagg_hi[rb + r][cb + lrow] = h;
        sagg_lo[rb + r][cb + lrow] = f2bf(v - bf2f(h));
    }

    // Phase B
    acc = (f32x4){0.f, 0.f, 0.f, 0.f};
    PIPE(4, LDB, COMPB)
    {
        int hp = cb + lrow;
        float w0 = mwl[(H + 0) * H + hp];
        float w1 = mwl[(H + 1) * H + hp];
        float w2 = mwl[(H + 2) * H + hp];
        float mb = mbl[hp];
#pragma unroll
        for (int r = 0; r < 4; ++r) {
            int jl = j0 + rb + r;
            float v = acc[r] + deg[jl] * mb
                    + sragg[rb + r][0] * w0 + sragg[rb + r][1] * w1
                    + sragg[rb + r][2] * w2;
            u16 h = f2bf(v);
            smsg_hi[rb + r][hp] = h;
            smsg_lo[rb + r][hp] = f2bf(v - bf2f(h));
        }
    }

    // Phase C
    acc = (f32x4){0.f, 0.f, 0.f, 0.f};
    PIPE(8, LDC, COMPC)
    {
        float ub = ubl[cb + lrow];
#pragma unroll
        for (int r = 0; r < 4; ++r) {
            float v = fmaxf(acc[r] + ub, 0.f);
            if constexpr (LAST) {
                u16 h = f2bf(v);
                sagg_hi[rb + r][cb + lrow] = h;
                sagg_lo[rb + r][cb + lrow] = f2bf(v - bf2f(h));
            } else {
                sout[rb + r][cb + lrow] = v;
            }
        }
    }
    __syncthreads();

    if constexpr (!LAST) {
        {
            int row = t >> 5, h0 = (t & 31) * 4;
            int gr = gb + j0 + row;
            float4 v = *(const float4*)&sout[row][h0];
            float xs[4] = {v.x, v.y, v.z, v.w};
            short4v ph, pl;
#pragma unroll
            for (int c = 0; c < 4; ++c) {
                u16 h = f2bf(xs[c]);
                ph[c] = (short)h;
                pl[c] = (short)f2bf(xs[c] - bf2f(h));
            }
            *(short4v*)&oR_hi[(size_t)gr * H + h0] = ph;
            *(short4v*)&oR_lo[(size_t)gr * H + h0] = pl;
        }
        {
            int hh = t >> 2, jj = (t & 3) * 4;
            short4v th, tl;
#pragma unroll
            for (int r = 0; r < 4; ++r) {
                float x = sout[jj + r][hh];
                u16 h = f2bf(x);
                th[r] = (short)h;
                tl[r] = (short)f2bf(x - bf2f(h));
            }
            size_t o = (size_t)b * H * N + (size_t)hh * N + j0 + jj;
            *(short4v*)&oT_hi[o] = th;
            *(short4v*)&oT_lo[o] = tl;
        }
    } else {
        const int br = ((wave >= 4) ? 64 : 0) + (wave & 3) * 16 + lrow;
        acc = (f32x4){0.f, 0.f, 0.f, 0.f};
        PIPE(4, LDD, COMPD)
#pragma unroll
        for (int r = 0; r < 4; ++r) sout[rb + r][br] = acc[r];
        __syncthreads();
        int row = t >> 5, c0 = (t & 31) * 4;
        int gr = gb + j0 + row;
        float4 v = *(const float4*)&sout[row][c0];
        if (c0 < 64) *(float4*)&hi_out[(size_t)gr * FH + c0] = v;
        else         *(float4*)&hj_out[(size_t)gr * FH + (c0 - 64)] = v;
    }
#undef WRX
#undef LDA
#undef LDB
#undef LDC
#undef LDD
#undef COMPA
#undef COMPB
#undef COMPC
#undef COMPD
}

// ---------------------------------------------------------------------------
// k_final R13: operand delivery rebuilt.
//  - weights/b1/W2 read DIRECTLY from global in-loop (thread-uniform addrs ->
//    scalar s_load path through constant cache; zero LDS, zero VGPR loads)
//  - his/hjs staged in LDS, read as float4 (rows 16B-aligned; hjs stride 68)
//  Per 4-f chunk: 2 ds_read_b128 + 9 uniform loads + ~52 VALU
//  (was: 44 ds_read_b32 + ~40 VALU -> LDS-issue-bound at 20 us, VALUBusy 86%)
__global__ __launch_bounds__(256) void k_final(
    const float* __restrict__ hi, const float* __restrict__ hj,
    const float* __restrict__ e0p, const float* __restrict__ e1p,
    const float* __restrict__ e2p, const float* __restrict__ temporal,
    const float* __restrict__ W1, const float* __restrict__ b1,
    const float* __restrict__ W2, const float* __restrict__ b2,
    float* __restrict__ flows) {
    __shared__ __align__(16) float his[8][FH];        // 256B rows
    __shared__ __align__(16) float hjs[32][FH + 4];   // 272B rows (16B mult)
    int blk = blockIdx.x;
    int jt = blk & 7, it = (blk >> 3) & 31, b = blk >> 8;
    int tid = threadIdx.x;
#pragma unroll
    for (int u = 0; u < 2; ++u) {
        int idx = u * 256 + tid;
        his[idx >> 6][idx & 63] = hi[((size_t)(b * N) + it * 8 + (idx >> 6)) * FH + (idx & 63)];
    }
#pragma unroll
    for (int u = 0; u < 8; ++u) {
        int idx = u * 256 + tid;
        hjs[idx >> 6][idx & 63] = hj[((size_t)(b * N) + jt * 32 + (idx >> 6)) * FH + (idx & 63)];
    }
    __syncthreads();
    int ti = tid >> 5, tj = tid & 31;
    int i = it * 8 + ti, j = jt * 32 + tj;
    size_t pij = ((size_t)(b * N) + i) * N + j;
    float e0 = e0p[pij], e1 = e1p[pij], e2 = e2p[pij];
    float4 tf = *(const float4*)(temporal + pij * TD);
    const float* Wx = W1 + (2 * H) * FH;   // rows: wr0,wr1,wr2,wt0,wt1,wt2,wt3
    float acc = 0.f;
#pragma unroll
    for (int f0 = 0; f0 < FH; f0 += 4) {
        float4 h4 = *(const float4*)&his[ti][f0];
        float4 g4 = *(const float4*)&hjs[tj][f0];
        float4 r0 = *(const float4*)(Wx + 0 * FH + f0);
        float4 r1 = *(const float4*)(Wx + 1 * FH + f0);
        float4 r2 = *(const float4*)(Wx + 2 * FH + f0);
        float4 t0 = *(const float4*)(Wx + 3 * FH + f0);
        float4 t1 = *(const float4*)(Wx + 4 * FH + f0);
        float4 t2 = *(const float4*)(Wx + 5 * FH + f0);
        float4 t3 = *(const float4*)(Wx + 6 * FH + f0);
        float4 bb = *(const float4*)(b1 + f0);
        float4 w2 = *(const float4*)(W2 + f0);
        float v;
        v = h4.x + g4.x + bb.x + e0 * r0.x + e1 * r1.x + e2 * r2.x
          + tf.x * t0.x + tf.y * t1.x + tf.z * t2.x + tf.w * t3.x;
        acc += fmaxf(v, 0.f) * w2.x;
        v = h4.y + g4.y + bb.y + e0 * r0.y + e1 * r1.y + e2 * r2.y
          + tf.x * t0.y + tf.y * t1.y + tf.z * t2.y + tf.w * t3.y;
        acc += fmaxf(v, 0.f) * w2.y;
        v = h4.z + g4.z + bb.z + e0 * r0.z + e1 * r1.z + e2 * r2.z
          + tf.x * t0.z + tf.y * t1.z + tf.z * t2.z + tf.w * t3.z;
        acc += fmaxf(v, 0.f) * w2.z;
        v = h4.w + g4.w + bb.w + e0 * r0.w + e1 * r1.w + e2 * r2.w
          + tf.x * t0.w + tf.y * t1.w + tf.z * t2.w + tf.w * t3.w;
        acc += fmaxf(v, 0.f) * w2.w;
    }
    flows[pij] = fmaxf(acc + b2[0], 0.f);
}

// ---------------------------------------------------------------------------
extern "C" void kernel_launch(void* const* d_in, const int* in_sizes, int n_in,
                              void* d_out, int out_size, void* d_ws, size_t ws_size,
                              hipStream_t stream) {
    const float* nf       = (const float*)d_in[0];
    const float* edge     = (const float*)d_in[1];
    const float* temporal = (const float*)d_in[2];
    const int*   adj      = (const int*)d_in[3];
    const float* W_emb    = (const float*)d_in[4];
    const float* b_emb    = (const float*)d_in[5];
    const float* msg_W    = (const float*)d_in[6];
    const float* msg_b    = (const float*)d_in[7];
    const float* upd_W    = (const float*)d_in[8];
    const float* upd_b    = (const float*)d_in[9];
    const float* W1       = (const float*)d_in[10];
    const float* b1       = (const float*)d_in[11];
    const float* W2       = (const float*)d_in[12];
    const float* b2       = (const float*)d_in[13];
    float* out = (float*)d_out;
    (void)in_sizes; (void)n_in; (void)out_size; (void)ws_size;

    char* p = (char*)d_ws;
    auto take = [&](size_t bytes) { char* r = p; p += (bytes + 255) & ~(size_t)255; return r; };
    float* deg   = (float*)take(256 * 4);
    float* ragg  = (float*)take((size_t)M * 3 * 4);
    float* e0p   = (float*)take((size_t)B * N * N * 4);
    float* e1p   = (float*)take((size_t)B * N * N * 4);
    float* e2p   = (float*)take((size_t)B * N * N * 4);
    float* rp0   = (float*)take((size_t)B * N * N * 4);
    float* rp1   = (float*)take((size_t)B * N * N * 4);
    float* rp2   = (float*)take((size_t)B * N * N * 4);
    float* hi    = (float*)take((size_t)M * FH * 4);
    float* hj    = (float*)take((size_t)M * FH * 4);
    u16* eRhA = (u16*)take((size_t)M * H * 2);
    u16* eRlA = (u16*)take((size_t)M * H * 2);
    u16* eThA = (u16*)take((size_t)M * H * 2);
    u16* eTlA = (u16*)take((size_t)M * H * 2);
    u16* eRhB = (u16*)take((size_t)M * H * 2);
    u16* eRlB = (u16*)take((size_t)M * H * 2);
    u16* eThB = (u16*)take((size_t)M * H * 2);
    u16* eTlB = (u16*)take((size_t)M * H * 2);
    u16* WeTh = (u16*)take(3 * 16384 * 2);
    u16* WeTl = (u16*)take(3 * 16384 * 2);
    u16* UwTh = (u16*)take(3 * 32768 * 2);
    u16* UwTl = (u16*)take(3 * 32768 * 2);
    u16* W1Th = (u16*)take(16384 * 2);
    u16* W1Tl = (u16*)take(16384 * 2);

    k_setup<<<3072, 256, 0, stream>>>(edge, adj, nf, W_emb, b_emb,
                                      msg_W, upd_W, W1,
                                      e0p, e1p, e2p, rp0, rp1, rp2, deg,
                                      WeTh, WeTl, UwTh, UwTl, W1Th, W1Tl,
                                      eRhA, eRlA, eThA, eTlA);

    const int mwS = (H + 3) * H;
    k_layer<true, false><<<128, 512, 0, stream>>>(
        eRhA, eRlA, eThA, eTlA, adj, rp0, rp1, rp2, ragg, deg,
        WeTh + 0 * 16384, WeTl + 0 * 16384, msg_W + 0 * mwS, msg_b + 0 * H,
        UwTh + 0 * 32768, UwTl + 0 * 32768, upd_b + 0 * H,
        eRhB, eRlB, eThB, eTlB, W1Th, W1Tl, hi, hj);
    k_layer<false, false><<<128, 512, 0, stream>>>(
        eRhB, eRlB, eThB, eTlB, adj, rp0, rp1, rp2, ragg, deg,
        WeTh + 1 * 16384, WeTl + 1 * 16384, msg_W + 1 * mwS, msg_b + 1 * H,
        UwTh + 1 * 32768, UwTl + 1 * 32768, upd_b + 1 * H,
        eRhA, eRlA, eThA, eTlA, W1Th, W1Tl, hi, hj);
    k_layer<false, true><<<128, 512, 0, stream>>>(
        eRhA, eRlA, eThA, eTlA, adj, rp0, rp1, rp2, ragg, deg,
        WeTh + 2 * 16384, WeTl + 2 * 16384, msg_W + 2 * mwS, msg_b + 2 * H,
        UwTh + 2 * 32768, UwTl + 2 * 32768, upd_b + 2 * H,
        eRhB, eRlB, eThB, eTlB, W1Th, W1Tl, hi, hj);

    k_final<<<2048, 256, 0, stream>>>(hi, hj, e0p, e1p, e2p, temporal,
                                      W1, b1, W2, b2, out);
}